// Round 1
// 495.125 us; speedup vs baseline: 1.0121x; 1.0121x over previous
//
#include <hip/hip_runtime.h>
#include <hip/hip_bf16.h>
#include <math.h>

#define Bb 64
#define Nn 8192
#define MWw 128
#define Hh 8
#define Cc 1024
#define HDd 128
#define Kk 3

__device__ __forceinline__ float dot4(float4 a, float4 b) {
  return a.x*b.x + a.y*b.y + a.z*b.z + a.w*b.w;
}
__device__ __forceinline__ float sigmoidf_(float x) { return 1.0f / (1.0f + __expf(-x)); }
__device__ __forceinline__ float softplusf_(float x) {
  return fmaxf(x, 0.0f) + log1pf(__expf(-fabsf(x)));
}

// ---------------------------------------------------------------------------
// K1: one block per (b,h), 1024 threads. K-dim split 8 ways, LDS tree reduce
// for the two matvecs; final 8 scalar reductions via 6-step __shfl_xor wave
// reduce (1 barrier instead of 7). Block 0 additionally zeroes Z/S/out so the
// two hipMemsetAsync dispatches disappear from the graph.
// ---------------------------------------------------------------------------
__global__ __launch_bounds__(1024) void k_params(
    const float* __restrict__ cs, const float* __restrict__ W_head, const float* __restrict__ b_head,
    const float* __restrict__ W_reset, const float* __restrict__ b_reset,
    const float* __restrict__ W_key, const float* __restrict__ b_key,
    const float* __restrict__ W_beta, const float* __restrict__ b_beta,
    const float* __restrict__ W_gate, const float* __restrict__ b_gate,
    const float* __restrict__ W_shift, const float* __restrict__ b_shift,
    const float* __restrict__ W_gamma, const float* __restrict__ b_gamma,
    float* __restrict__ key_ws, float* __restrict__ params,
    float* __restrict__ zs, float* __restrict__ outp)
{
  int bh = blockIdx.x;
  int b = bh >> 3, h = bh & 7;
  int t = threadIdx.x;
  int d = t & 127, sl = t >> 7;   // 8 slices
  __shared__ float red[8][128];
  __shared__ float head_s[128];
  __shared__ float key_s[128];
  __shared__ float wred[16];

  if (bh == 0) {
    // zero Z (512) + S (512) contiguous, and out accumulator (8192 floats)
    zs[t] = 0.0f;
    #pragma unroll
    for (int j = 0; j < 8; ++j) outp[j * 1024 + t] = 0.0f;
  }

  const float* csb = cs + b * Cc + sl * 128;
  const float* w0 = W_head + (size_t)(sl * 128) * (Hh * HDd) + h * HDd + d;
  float acc = 0.0f;
  #pragma unroll 8
  for (int c = 0; c < 128; ++c) acc = fmaf(csb[c], w0[(size_t)c * (Hh * HDd)], acc);
  red[sl][d] = acc;
  __syncthreads();
  if (t < 128) {
    float s = b_head[h * HDd + t];
    #pragma unroll
    for (int j = 0; j < 8; ++j) s += red[j][t];
    head_s[t] = s;
  }
  __syncthreads();

  {
    const float* wk = W_key + (size_t)h * HDd * MWw + (sl * 16) * MWw + d;
    float ka = 0.0f;
    #pragma unroll
    for (int dd = 0; dd < 16; ++dd) ka = fmaf(head_s[sl * 16 + dd], wk[dd * MWw], ka);
    red[sl][d] = ka;
  }
  __syncthreads();
  if (t < 128) {
    float kv = b_key[h * MWw + t];
    #pragma unroll
    for (int j = 0; j < 8; ++j) kv += red[j][t];
    key_ws[bh * MWw + t] = kv;
    key_s[t] = kv;
  }
  __syncthreads();

  float hd = head_s[d];
  float v;
  switch (sl) {
    case 0: v = hd * W_reset[h * HDd + d]; break;
    case 1: v = hd * W_beta[h * HDd + d]; break;
    case 2: v = hd * W_gate[h * HDd + d]; break;
    case 3: v = hd * W_gamma[h * HDd + d]; break;
    case 4: v = hd * W_shift[(h * HDd + d) * Kk + 0]; break;
    case 5: v = hd * W_shift[(h * HDd + d) * Kk + 1]; break;
    case 6: v = hd * W_shift[(h * HDd + d) * Kk + 2]; break;
    default: v = key_s[d] * key_s[d]; break;
  }
  // 6-step butterfly: full 64-lane wave sum, then 2 partials per slice
  v += __shfl_xor(v, 1, 64);
  v += __shfl_xor(v, 2, 64);
  v += __shfl_xor(v, 4, 64);
  v += __shfl_xor(v, 8, 64);
  v += __shfl_xor(v, 16, 64);
  v += __shfl_xor(v, 32, 64);
  if ((t & 63) == 0) wred[t >> 6] = v;
  __syncthreads();
  if (t == 0) {
    float r0 = wred[0]  + wred[1];
    float r1 = wred[2]  + wred[3];
    float r2 = wred[4]  + wred[5];
    float r3 = wred[6]  + wred[7];
    float r4 = wred[8]  + wred[9];
    float r5 = wred[10] + wred[11];
    float r6 = wred[12] + wred[13];
    float r7 = wred[14] + wred[15];
    float reset = sigmoidf_(r0 + b_reset[h]);
    float beta  = softplusf_(r1 + b_beta[h]);
    float gate  = sigmoidf_(r2 + b_gate[h]);
    float gamma = 1.0f + softplusf_(r3 + b_gamma[h]);
    float a0 = r4 + b_shift[h * Kk + 0];
    float a1 = r5 + b_shift[h * Kk + 1];
    float a2 = r6 + b_shift[h * Kk + 2];
    float mx = fmaxf(a0, fmaxf(a1, a2));
    float e0 = __expf(a0 - mx), e1 = __expf(a1 - mx), e2 = __expf(a2 - mx);
    float inv = 1.0f / (e0 + e1 + e2);
    float* P = params + bh * 8;
    P[0] = reset; P[1] = beta; P[2] = gate; P[3] = gamma;
    P[4] = e0 * inv; P[5] = e1 * inv; P[6] = e2 * inv;
    P[7] = sqrtf(r7);
  }
}

// ---------------------------------------------------------------------------
// K2: big pass 1 over memory. Keys hand-hoisted into 128 VGPRs; #pragma
// unroll 1 outer loop keeps VGPR ~200 (2 waves/EU, no spill). e values are
// staged in LDS (stride 520 -> exactly 2-way banking = free) and written back
// coalesced as float4. atomicAdd Z. Memory-bound: ~285 MB at ~6.3 TB/s.
// ---------------------------------------------------------------------------
__global__ __launch_bounds__(256, 2) void k_sim(
    const float* __restrict__ mem, const float* __restrict__ key_ws,
    const float* __restrict__ params, float* __restrict__ e_ws, float* __restrict__ Z)
{
  int b = blockIdx.y, chunk = blockIdx.x;
  int t = threadIdx.x;
  int lane = t & 63, wid = t >> 6;
  int sub = lane & 7, rid = lane >> 3;
  __shared__ float4 keys[8][32];
  __shared__ float betas[8], knorms[8];
  __shared__ float e_s[8][520];   // [head][row-in-chunk], stride 520
  if (t < 8) { betas[t] = params[(b * 8 + t) * 8 + 1]; knorms[t] = params[(b * 8 + t) * 8 + 7]; }
  {
    int h = t >> 5, q = t & 31;
    keys[h][q] = ((const float4*)key_ws)[(b * 8 + h) * 32 + q];
  }
  __syncthreads();

  float4 kreg[8][4];
  #pragma unroll
  for (int h2 = 0; h2 < 8; ++h2) {
    kreg[h2][0] = keys[h2][sub];
    kreg[h2][1] = keys[h2][sub + 8];
    kreg[h2][2] = keys[h2][sub + 16];
    kreg[h2][3] = keys[h2][sub + 24];
  }

  const float4* m4 = (const float4*)mem + (size_t)b * Nn * 32;
  float beta = betas[sub], kn = knorms[sub];
  float zloc = 0.0f;
  int n0 = chunk * 512;

  #pragma unroll 1
  for (int itr = 0; itr < 8; ++itr) {
    int nb = n0 + itr * 64 + wid * 16 + rid;  // row for r=0; r adds 8
    float4 m[2][4];
    float nrm[2];
    float acc[2][8];
    #pragma unroll
    for (int r = 0; r < 2; ++r) {
      const float4* rp = m4 + (size_t)(nb + r * 8) * 32 + sub;
      m[r][0] = rp[0]; m[r][1] = rp[8]; m[r][2] = rp[16]; m[r][3] = rp[24];
    }
    #pragma unroll
    for (int r = 0; r < 2; ++r) {
      nrm[r] = dot4(m[r][0], m[r][0]) + dot4(m[r][1], m[r][1])
             + dot4(m[r][2], m[r][2]) + dot4(m[r][3], m[r][3]);
      #pragma unroll
      for (int h2 = 0; h2 < 8; ++h2) {
        acc[r][h2] = dot4(m[r][0], kreg[h2][0]) + dot4(m[r][1], kreg[h2][1])
                   + dot4(m[r][2], kreg[h2][2]) + dot4(m[r][3], kreg[h2][3]);
      }
    }
    #pragma unroll
    for (int r = 0; r < 2; ++r) {
      float* a = acc[r];
      bool h1 = (sub & 1) != 0;
      float v40 = (h1 ? a[1] : a[0]) + __shfl_xor(h1 ? a[0] : a[1], 1, 64);
      float v41 = (h1 ? a[3] : a[2]) + __shfl_xor(h1 ? a[2] : a[3], 1, 64);
      float v42 = (h1 ? a[5] : a[4]) + __shfl_xor(h1 ? a[4] : a[5], 1, 64);
      float v43 = (h1 ? a[7] : a[6]) + __shfl_xor(h1 ? a[6] : a[7], 1, 64);
      bool h2b = (sub & 2) != 0;
      float v20 = (h2b ? v41 : v40) + __shfl_xor(h2b ? v40 : v41, 2, 64);
      float v21 = (h2b ? v43 : v42) + __shfl_xor(h2b ? v42 : v43, 2, 64);
      bool h4 = (sub & 4) != 0;
      float dsum = (h4 ? v21 : v20) + __shfl_xor(h4 ? v20 : v21, 4, 64);
      float nr = nrm[r];
      nr += __shfl_xor(nr, 1, 64);
      nr += __shfl_xor(nr, 2, 64);
      nr += __shfl_xor(nr, 4, 64);
      float s = beta * dsum / (kn * sqrtf(nr) + 1e-8f);
      float e = __expf(s - beta);
      e_s[sub][(nb + r * 8) - n0] = e;   // lane addr = sub*520 + nloc -> 2-way banks, free
      zloc += e;
    }
  }
  zloc += __shfl_xor(zloc, 8, 64);
  zloc += __shfl_xor(zloc, 16, 64);
  zloc += __shfl_xor(zloc, 32, 64);
  if (lane < 8) atomicAdd(&Z[b * 8 + lane], zloc);
  __syncthreads();

  // coalesced float4 writeback: 8 heads x 512 rows = 1024 float4 / 256 thr
  #pragma unroll
  for (int j = 0; j < 4; ++j) {
    int idx = j * 256 + t;
    int h = idx >> 7, q = idx & 127;
    float4 v = *(const float4*)&e_s[h][q * 4];
    ((float4*)(e_ws + (size_t)(b * 8 + h) * Nn + n0))[q] = v;
  }
}

// ---------------------------------------------------------------------------
// K3: w_g blend + circular conv (K=3) + gamma power, float4 throughout.
// LDS layout: wg[l] = w_g[n0+l] for l in [0,2048); wg[2048] = w_g[n0-1],
// wg[2049] = w_g[n0+2048] (circular halos). Aligned b128 LDS reads.
// w_pow written into d_out's new_w region (normalized in K4). atomicAdd S.
// ---------------------------------------------------------------------------
__global__ __launch_bounds__(256) void k_conv(
    const float* __restrict__ e_ws, const float* __restrict__ prev, const float* __restrict__ defw,
    const float* __restrict__ params, const float* __restrict__ Z,
    float* __restrict__ wp, float* __restrict__ S)
{
  int chunk = blockIdx.x, h = blockIdx.y, b = blockIdx.z;
  int bh = b * 8 + h, t = threadIdx.x;
  __shared__ float wg[2052];
  const float* P = params + bh * 8;
  float reset = P[0], gate = P[2], gamma = P[3], s0 = P[4], s1 = P[5], s2 = P[6];
  float invZg = gate / Z[bh];
  float om = 1.0f - gate, omr = 1.0f - reset;
  size_t base = (size_t)bh * Nn;
  int n0 = chunk * 2048;

  const float4* e4p = (const float4*)(e_ws + base + n0);
  const float4* p4p = (const float4*)(prev + base + n0);
  const float4* d4p = (const float4*)(defw + base + n0);
  #pragma unroll
  for (int it = 0; it < 2; ++it) {
    int idx4 = it * 256 + t;
    float4 e = e4p[idx4], pv = p4p[idx4], dv = d4p[idx4];
    float4 w;
    w.x = invZg * e.x + om * (pv.x * omr + dv.x * reset);
    w.y = invZg * e.y + om * (pv.y * omr + dv.y * reset);
    w.z = invZg * e.z + om * (pv.z * omr + dv.z * reset);
    w.w = invZg * e.w + om * (pv.w * omr + dv.w * reset);
    *(float4*)&wg[idx4 * 4] = w;
  }
  if (t < 2) {
    int n = (t == 0) ? ((n0 + Nn - 1) & (Nn - 1)) : ((n0 + 2048) & (Nn - 1));
    float e = e_ws[base + n], pv = prev[base + n], dv = defw[base + n];
    wg[2048 + t] = invZg * e + om * (pv * omr + dv * reset);
  }
  __syncthreads();

  float sacc = 0.0f;
  float4* wp4 = (float4*)(wp + base + n0);
  #pragma unroll
  for (int it = 0; it < 2; ++it) {
    int idx4 = it * 256 + t;
    int l = idx4 * 4;
    float4 c = *(const float4*)&wg[l];
    float left  = (l == 0)        ? wg[2048] : wg[l - 1];
    float right = (l + 4 == 2048) ? wg[2049] : wg[l + 4];
    // w_s[n] = s0*w_g[n+1] + s1*w_g[n] + s2*w_g[n-1]  (jnp.roll semantics)
    float4 wsv;
    wsv.x = s0 * c.y   + s1 * c.x + s2 * left;
    wsv.y = s0 * c.z   + s1 * c.y + s2 * c.x;
    wsv.z = s0 * c.w   + s1 * c.z + s2 * c.y;
    wsv.w = s0 * right + s1 * c.w + s2 * c.z;
    float4 o;
    o.x = __expf(gamma * __logf(wsv.x + 1e-8f));
    o.y = __expf(gamma * __logf(wsv.y + 1e-8f));
    o.z = __expf(gamma * __logf(wsv.z + 1e-8f));
    o.w = __expf(gamma * __logf(wsv.w + 1e-8f));
    wp4[idx4] = o;
    sacc += o.x + o.y + o.z + o.w;
  }
  sacc += __shfl_xor(sacc, 1, 64);
  sacc += __shfl_xor(sacc, 2, 64);
  sacc += __shfl_xor(sacc, 4, 64);
  sacc += __shfl_xor(sacc, 8, 64);
  sacc += __shfl_xor(sacc, 16, 64);
  sacc += __shfl_xor(sacc, 32, 64);
  __shared__ float sred[4];
  if ((t & 63) == 0) sred[t >> 6] = sacc;
  __syncthreads();
  if (t == 0) atomicAdd(&S[bh], sred[0] + sred[1] + sred[2] + sred[3]);
}

// ---------------------------------------------------------------------------
// K4 (fused norm+read): each block owns 512 rows of batch b.
// Phase 1 (vectorized): normalize new_w in place for all 8 heads via float4
//          (grp 0 handles h0-3, grp 1 handles h4-7 for all 128 float4 cols),
//          partial merged coefficients staged in red4, combined into coef_s.
// Phase 2: out[b,:] += sum_n coef[n] * mem[b,n,:]  (float4, LDS reduce,
//          128 atomics/block).
// ---------------------------------------------------------------------------
__global__ __launch_bounds__(256) void k_readnorm(
    const float* __restrict__ mem, float* __restrict__ wp, const float* __restrict__ S,
    const float* __restrict__ merge_w, float* __restrict__ out)
{
  int b = blockIdx.y; int n0 = blockIdx.x * 512; int t = threadIdx.x;
  __shared__ float kh[8], invS_s[8];
  __shared__ float coef_s[512];
  __shared__ float4 red4[256];   // reused: phase-1 coef partials, then reduce
  if (t < 8) {
    float s = S[b * 8 + t];
    invS_s[t] = 1.0f / s;
    kh[t] = merge_w[t] / s;
  }
  __syncthreads();

  // Phase 1: float4 normalize + merged coef. grp in {0,1} covers 4 heads each.
  int col = t & 127, grp = t >> 7;
  float4 cf = make_float4(0.0f, 0.0f, 0.0f, 0.0f);
  #pragma unroll
  for (int hh = 0; hh < 4; ++hh) {
    int h = grp * 4 + hh;
    float4* wph = (float4*)(wp + (size_t)(b * 8 + h) * Nn + n0);
    float4 v = wph[col];
    float is = invS_s[h], k = kh[h];
    float4 o;
    o.x = v.x * is; o.y = v.y * is; o.z = v.z * is; o.w = v.w * is;
    wph[col] = o;
    cf.x = fmaf(k, v.x, cf.x);
    cf.y = fmaf(k, v.y, cf.y);
    cf.z = fmaf(k, v.z, cf.z);
    cf.w = fmaf(k, v.w, cf.w);
  }
  red4[grp * 128 + col] = cf;
  __syncthreads();
  if (t < 128) {
    float4 a = red4[t], c = red4[128 + t];
    float4 s4;
    s4.x = a.x + c.x; s4.y = a.y + c.y; s4.z = a.z + c.z; s4.w = a.w + c.w;
    *(float4*)&coef_s[t * 4] = s4;
  }
  __syncthreads();

  // Phase 2: read pass
  int w4 = t & 31, rg = t >> 5;
  const float4* m4 = (const float4*)mem + (size_t)b * Nn * 32;
  float4 acc = make_float4(0.0f, 0.0f, 0.0f, 0.0f);
  #pragma unroll 4
  for (int it = 0; it < 64; ++it) {
    int nl = it * 8 + rg;
    float c = coef_s[nl];
    float4 m = m4[(size_t)(n0 + nl) * 32 + w4];
    acc.x = fmaf(c, m.x, acc.x);
    acc.y = fmaf(c, m.y, acc.y);
    acc.z = fmaf(c, m.z, acc.z);
    acc.w = fmaf(c, m.w, acc.w);
  }
  red4[t] = acc;
  __syncthreads();
  if (t < 32) {
    float4 s = red4[t];
    #pragma unroll
    for (int j = 1; j < 8; ++j) {
      float4 o = red4[t + 32 * j];
      s.x += o.x; s.y += o.y; s.z += o.z; s.w += o.w;
    }
    atomicAdd(&out[b * MWw + t * 4 + 0], s.x);
    atomicAdd(&out[b * MWw + t * 4 + 1], s.y);
    atomicAdd(&out[b * MWw + t * 4 + 2], s.z);
    atomicAdd(&out[b * MWw + t * 4 + 3], s.w);
  }
}

extern "C" void kernel_launch(void* const* d_in, const int* in_sizes, int n_in,
                              void* d_out, int out_size, void* d_ws, size_t ws_size,
                              hipStream_t stream)
{
  const float* cs      = (const float*)d_in[0];
  const float* mem     = (const float*)d_in[1];
  const float* prev    = (const float*)d_in[2];
  const float* defw    = (const float*)d_in[3];
  const float* W_head  = (const float*)d_in[4];
  const float* b_head  = (const float*)d_in[5];
  const float* W_reset = (const float*)d_in[6];
  const float* b_reset = (const float*)d_in[7];
  const float* W_key   = (const float*)d_in[8];
  const float* b_key   = (const float*)d_in[9];
  const float* W_beta  = (const float*)d_in[10];
  const float* b_beta  = (const float*)d_in[11];
  const float* W_gate  = (const float*)d_in[12];
  const float* b_gate  = (const float*)d_in[13];
  const float* W_shift = (const float*)d_in[14];
  const float* b_shift = (const float*)d_in[15];
  const float* W_gamma = (const float*)d_in[16];
  const float* b_gamma = (const float*)d_in[17];
  const float* merge_w = (const float*)d_in[18];

  float* out  = (float*)d_out;          // [B,MW]
  float* neww = out + Bb * MWw;         // [B,H,N] — w_pow scratch then final

  float* ws_f   = (float*)d_ws;
  float* key_ws = ws_f;                     // 65536 floats
  float* params = ws_f + 65536;             // 4096
  float* Zacc   = ws_f + 69632;             // 512
  float* Sacc   = ws_f + 70144;             // 512 (contiguous with Zacc)
  float* e_ws   = ws_f + 70656;             // 4194304

  // Z/S/out zeroing folded into k_params block 0 (removes 2 fill dispatches)
  k_params<<<dim3(Bb * Hh), dim3(1024), 0, stream>>>(
      cs, W_head, b_head, W_reset, b_reset, W_key, b_key, W_beta, b_beta,
      W_gate, b_gate, W_shift, b_shift, W_gamma, b_gamma, key_ws, params,
      Zacc, out);
  k_sim<<<dim3(16, Bb), dim3(256), 0, stream>>>(mem, key_ws, params, e_ws, Zacc);
  k_conv<<<dim3(4, Hh, Bb), dim3(256), 0, stream>>>(e_ws, prev, defw, params, Zacc, neww, Sacc);
  k_readnorm<<<dim3(16, Bb), dim3(256), 0, stream>>>(mem, neww, Sacc, merge_w, out);
}